// Round 9
// baseline (160.128 us; speedup 1.0000x reference)
//
#include <hip/hip_runtime.h>

// Clang ext_vector float4 — required for __builtin_nontemporal_load.
typedef float f4 __attribute__((ext_vector_type(4)));

// Fused SSD-loss kernel. One launch.
//
// Read-path findings (R0-R8): every read mechanism on gfx950 — VGPR-return
// at pipeline depth 2/4/8, blocked vs chip-wide-sweep layouts,
// sched_group_barrier directives, nontemporal policy, and the LDS-return
// path (global_load_lds w/ counted vmcnt, triple-buffered) — lands at
// 3.1-3.5 TB/s effective read for this 134 MB two-stream reduction.
// That equals the read component of the m13 copy ceiling (6.29 total =
// 3.15r+3.15w) while write-only fills in the same capture do 6.5 TB/s:
// the read-direction supply is the wall, insensitive to request structure.
// FETCH_SIZE confirms minimum traffic (no over-fetch). Best variant was
// R6 (nontemporal sweep, ~38-39 us, ~3.45 TB/s) — restored here.
//
// This revision only removes the second launch: each block atomically
// accumulates its scaled partial into out[0] (harness memsets out=0 before
// the launch). 2047 float atomics total => no contention; ordering
// nondeterminism ~1e-6, threshold 8e-2.
//
// 2047 blocks x 256 threads, stride 524,032 float4s, 8 iterations exactly
// covers 4,192,256 = B*S*2/4. n4 passed at runtime keeps the loop rolled
// (the proven-best codegen); no bounds checks needed since coverage is
// exact and the loop condition handles termination.
__global__ __launch_bounds__(256, 4) void ssd_fused(const f4* __restrict__ p,
                                                    const f4* __restrict__ t,
                                                    float* __restrict__ out,
                                                    float scale, int n4) {
    const int tid = threadIdx.x;
    const int stride = gridDim.x * 256;   // runtime => loop stays rolled
    int i = blockIdx.x * 256 + tid;

    float acc0 = 0.f, acc1 = 0.f, acc2 = 0.f, acc3 = 0.f;
    for (; i < n4; i += stride) {
        f4 a = __builtin_nontemporal_load(p + i);
        f4 b = __builtin_nontemporal_load(t + i);
        float dx = a.x - b.x; acc0 += dx * dx;
        float dy = a.y - b.y; acc1 += dy * dy;
        float dz = a.z - b.z; acc2 += dz * dz;
        float dw = a.w - b.w; acc3 += dw * dw;
    }
    float acc = (acc0 + acc1) + (acc2 + acc3);

    // wave-64 reduce
    #pragma unroll
    for (int off = 32; off > 0; off >>= 1)
        acc += __shfl_down(acc, off, 64);

    __shared__ float wave_sums[4];
    const int lane = tid & 63;
    const int wave = tid >> 6;
    if (lane == 0) wave_sums[wave] = acc;
    __syncthreads();

    if (tid == 0) {
        float block_sum = (wave_sums[0] + wave_sums[1]) + (wave_sums[2] + wave_sums[3]);
        atomicAdd(out, block_sum * scale);   // device-scope by default on CDNA
    }
}

extern "C" void kernel_launch(void* const* d_in, const int* in_sizes, int n_in,
                              void* d_out, int out_size, void* d_ws, size_t ws_size,
                              hipStream_t stream) {
    const float* pred = (const float*)d_in[0];
    const float* targ = (const float*)d_in[1];
    float* out = (float*)d_out;

    const int B = 4096;
    const int S = 2047;  // 2*d+1 with d=1023 — slice covers the whole tensor
    const float scale = 1.0f / ((float)S * (float)B);
    const int n4 = B * S * 2 / 4;  // 4,192,256 float4 pairs = 2047*256*8 exactly

    ssd_fused<<<2047, 256, 0, stream>>>((const f4*)pred, (const f4*)targ,
                                        out, scale, n4);
}

// Round 10
// 143.863 us; speedup vs baseline: 1.1131x; 1.1131x over previous
//
#include <hip/hip_runtime.h>

// Clang ext_vector float4 — required for __builtin_nontemporal_load.
typedef float f4 __attribute__((ext_vector_type(4)));

// Kernel 1: per-block partial sums of squared differences.
//
// FINAL CONFIGURATION (revert to R6, the best measured: bench 144.2 us).
//
// Findings R0-R9: every read mechanism on gfx950 — VGPR-return at pipeline
// depth 2/4/8, blocked vs chip-wide-sweep layouts, sched_group_barrier
// directives, nontemporal policy, LDS-return (global_load_lds, counted
// vmcnt, triple-buffered), and single-kernel fusion with atomics — lands
// at 3.1-3.5 TB/s effective read for this 134 MB two-stream reduction.
// That equals the read component of the m13 copy ceiling (6.29 TB/s total
// = 3.15r + 3.15w) while write-only fills in the same captures hit
// 6.5 TB/s: the read-direction supply is the wall, insensitive to request
// structure. FETCH_SIZE = 65.5 MB/dispatch confirms minimum HBM traffic.
// NT loads (this variant) were the only positive delta (~4 us), presumably
// by not displacing the L3-resident co-tenant lines. Fusion (R9) regressed
// bench 144->160 (atomic drain + per-iter out-memset in the graph) — two
// launches with a deterministic finalize is the best structure.
__global__ __launch_bounds__(256, 4) void ssd_partials(const f4* __restrict__ p,
                                                       const f4* __restrict__ t,
                                                       float* __restrict__ ws,
                                                       int n4) {
    const int tid = threadIdx.x;
    const int stride = gridDim.x * 256;   // runtime => loop stays rolled
    int i = blockIdx.x * 256 + tid;

    float acc0 = 0.f, acc1 = 0.f, acc2 = 0.f, acc3 = 0.f;
    for (; i < n4; i += stride) {
        f4 a = __builtin_nontemporal_load(p + i);
        f4 b = __builtin_nontemporal_load(t + i);
        float dx = a.x - b.x; acc0 += dx * dx;
        float dy = a.y - b.y; acc1 += dy * dy;
        float dz = a.z - b.z; acc2 += dz * dz;
        float dw = a.w - b.w; acc3 += dw * dw;
    }
    float acc = (acc0 + acc1) + (acc2 + acc3);

    // wave-64 reduce
    #pragma unroll
    for (int off = 32; off > 0; off >>= 1)
        acc += __shfl_down(acc, off, 64);

    __shared__ float wave_sums[4];
    const int lane = tid & 63;
    const int wave = tid >> 6;
    if (lane == 0) wave_sums[wave] = acc;
    __syncthreads();

    if (tid == 0)
        ws[blockIdx.x] = (wave_sums[0] + wave_sums[1]) + (wave_sums[2] + wave_sums[3]);
}

// Kernel 2: reduce 2047 partials -> out[0] = sum * scale.
// Single block of 256; every ws slot read was written by kernel 1.
// Deterministic read order => bit-exact across runs (absmax 0).
__global__ __launch_bounds__(256) void ssd_finalize(const float* __restrict__ ws,
                                                    float* __restrict__ out,
                                                    float scale) {
    const int tid = threadIdx.x;
    float acc = 0.f;
    #pragma unroll
    for (int k = 0; k < 8; ++k) {
        int idx = tid + k * 256;
        if (idx < 2047) acc += ws[idx];
    }

    #pragma unroll
    for (int off = 32; off > 0; off >>= 1)
        acc += __shfl_down(acc, off, 64);

    __shared__ float wave_sums[4];
    const int lane = tid & 63;
    const int wave = tid >> 6;
    if (lane == 0) wave_sums[wave] = acc;
    __syncthreads();

    if (tid == 0)
        out[0] = ((wave_sums[0] + wave_sums[1]) + (wave_sums[2] + wave_sums[3])) * scale;
}

extern "C" void kernel_launch(void* const* d_in, const int* in_sizes, int n_in,
                              void* d_out, int out_size, void* d_ws, size_t ws_size,
                              hipStream_t stream) {
    const float* pred = (const float*)d_in[0];
    const float* targ = (const float*)d_in[1];
    float* out = (float*)d_out;
    float* ws = (float*)d_ws;  // needs 2047 floats = 8188 B

    const int B = 4096;
    const int S = 2047;  // 2*d+1 with d=1023 — slice covers the whole tensor
    const float scale = 1.0f / ((float)S * (float)B);
    const int n4 = B * S * 2 / 4;  // 4,192,256 float4 pairs = 2047*256*8 exactly

    ssd_partials<<<2047, 256, 0, stream>>>((const f4*)pred,
                                           (const f4*)targ, ws, n4);
    ssd_finalize<<<1, 256, 0, stream>>>(ws, out, scale);
}